// Round 1
// baseline (964.693 us; speedup 1.0000x reference)
//
#include <hip/hip_runtime.h>
#include <hip/hip_bf16.h>
#include <math.h>

// Problem constants (from reference): B=2, T=2048, C=1024, H=16, Dh=64
#define GB 2
#define GT_SEQ 2048
#define GC 1024
#define GH 16
#define GDH 64
#define GM (GB * GT_SEQ)      // 4096 rows

// ---------------- GEMM: C[M][N] = A[M][K] @ B[N][K]^T + bias[N] ----------------
// 128x128 output tile, K-tile 64, 256 threads, 8x8 accum per thread.
#define GT 128
#define GKT 64
#define GSTR (GT + 4)   // 132 floats -> 528B row stride, 16B-aligned

__global__ __launch_bounds__(256) void gemm_bt_bias(
    const float* __restrict__ A, const float* __restrict__ B,
    const float* __restrict__ bias, float* __restrict__ C,
    int M, int N, int K)
{
    __shared__ float As[GKT][GSTR];   // k-major: As[k][m]
    __shared__ float Bs[GKT][GSTR];   // k-major: Bs[k][n]

    const int tid = threadIdx.x;
    const int tx = tid & 15;
    const int ty = tid >> 4;
    const int m0 = blockIdx.y * GT;
    const int n0 = blockIdx.x * GT;

    float acc[8][8];
#pragma unroll
    for (int i = 0; i < 8; ++i)
#pragma unroll
        for (int j = 0; j < 8; ++j) acc[i][j] = 0.f;

    const int lk = (tid & 15) * 4;   // k offset this thread loads
    const int lr = tid >> 4;         // base row

    for (int k0 = 0; k0 < K; k0 += GKT) {
#pragma unroll
        for (int p = 0; p < 8; ++p) {
            const int row = lr + p * 16;
            const float4 va = *reinterpret_cast<const float4*>(
                &A[(size_t)(m0 + row) * K + (k0 + lk)]);
            As[lk + 0][row] = va.x;
            As[lk + 1][row] = va.y;
            As[lk + 2][row] = va.z;
            As[lk + 3][row] = va.w;
            const float4 vb = *reinterpret_cast<const float4*>(
                &B[(size_t)(n0 + row) * K + (k0 + lk)]);
            Bs[lk + 0][row] = vb.x;
            Bs[lk + 1][row] = vb.y;
            Bs[lk + 2][row] = vb.z;
            Bs[lk + 3][row] = vb.w;
        }
        __syncthreads();

#pragma unroll 4
        for (int kk = 0; kk < GKT; ++kk) {
            const float4 a0 = *reinterpret_cast<const float4*>(&As[kk][ty * 8]);
            const float4 a1 = *reinterpret_cast<const float4*>(&As[kk][ty * 8 + 4]);
            const float4 b0 = *reinterpret_cast<const float4*>(&Bs[kk][tx * 8]);
            const float4 b1 = *reinterpret_cast<const float4*>(&Bs[kk][tx * 8 + 4]);
            const float av[8] = {a0.x, a0.y, a0.z, a0.w, a1.x, a1.y, a1.z, a1.w};
            const float bv[8] = {b0.x, b0.y, b0.z, b0.w, b1.x, b1.y, b1.z, b1.w};
#pragma unroll
            for (int i = 0; i < 8; ++i)
#pragma unroll
                for (int j = 0; j < 8; ++j)
                    acc[i][j] = fmaf(av[i], bv[j], acc[i][j]);
        }
        __syncthreads();
    }

    // epilogue: bias + coalesced float4 stores
#pragma unroll
    for (int i = 0; i < 8; ++i) {
        const size_t crow = (size_t)(m0 + ty * 8 + i) * N + (n0 + tx * 8);
        float4 o0, o1;
        o0.x = acc[i][0] + bias[n0 + tx * 8 + 0];
        o0.y = acc[i][1] + bias[n0 + tx * 8 + 1];
        o0.z = acc[i][2] + bias[n0 + tx * 8 + 2];
        o0.w = acc[i][3] + bias[n0 + tx * 8 + 3];
        o1.x = acc[i][4] + bias[n0 + tx * 8 + 4];
        o1.y = acc[i][5] + bias[n0 + tx * 8 + 5];
        o1.z = acc[i][6] + bias[n0 + tx * 8 + 6];
        o1.w = acc[i][7] + bias[n0 + tx * 8 + 7];
        *reinterpret_cast<float4*>(&C[crow]) = o0;
        *reinterpret_cast<float4*>(&C[crow + 4]) = o1;
    }
}

// ---------------- Flash attention (causal, online softmax) ----------------
// Block: 256 threads. One block per (b, h, 64-row Q tile). K/V tiles of 64.
// Thread (tx,ty): rows ty*4..+3, cols tx*4..+3 of the 64x64 tile.
#define ASTR 68   // 68 floats -> 272B stride, 16B-aligned

__global__ __launch_bounds__(256) void flash_attn(
    const float* __restrict__ qkv,   // [B*T][3C]: q | k | v per row
    float* __restrict__ O)           // [B*T][C]
{
    __shared__ float Qs[64][ASTR];   // [d][r]  (transposed)
    __shared__ float Ks[64][ASTR];   // [d][c]  (transposed)
    __shared__ float Vs[64][ASTR];   // [j][d]  (natural)
    __shared__ float Ps[64][ASTR];   // [r][j]

    const int tid = threadIdx.x;
    const int tx = tid & 15;
    const int ty = tid >> 4;
    const int qt = blockIdx.x;            // Q tile index, 0..31
    const int bh = blockIdx.y;            // 0..31
    const int b  = bh >> 4;
    const int h  = bh & 15;
    const int q0 = qt * 64;

    const int ld = (tid & 15) * 4;        // d offset loaded by this thread
    const int lr = tid >> 4;              // base row loaded

    // load Q tile transposed into Qs[d][r]
#pragma unroll
    for (int p = 0; p < 4; ++p) {
        const int r = lr + p * 16;
        const float4 v = *reinterpret_cast<const float4*>(
            &qkv[(size_t)(b * GT_SEQ + q0 + r) * (3 * GC) + h * GDH + ld]);
        Qs[ld + 0][r] = v.x;
        Qs[ld + 1][r] = v.y;
        Qs[ld + 2][r] = v.z;
        Qs[ld + 3][r] = v.w;
    }

    float m_i[4], l_i[4], acc[4][4];
#pragma unroll
    for (int i = 0; i < 4; ++i) {
        m_i[i] = -1e30f;
        l_i[i] = 0.f;
#pragma unroll
        for (int j = 0; j < 4; ++j) acc[i][j] = 0.f;
    }

    for (int kt = 0; kt <= qt; ++kt) {
        const int k0 = kt * 64;
        __syncthreads();   // Ks/Vs/Ps free to overwrite (and Qs visible on kt==0)

        // load K tile (transposed) and V tile (natural)
#pragma unroll
        for (int p = 0; p < 4; ++p) {
            const int r = lr + p * 16;
            const size_t base = (size_t)(b * GT_SEQ + k0 + r) * (3 * GC) + h * GDH + ld;
            const float4 kv = *reinterpret_cast<const float4*>(&qkv[base + GC]);
            Ks[ld + 0][r] = kv.x;
            Ks[ld + 1][r] = kv.y;
            Ks[ld + 2][r] = kv.z;
            Ks[ld + 3][r] = kv.w;
            const float4 vv = *reinterpret_cast<const float4*>(&qkv[base + 2 * GC]);
            *reinterpret_cast<float4*>(&Vs[r][ld]) = vv;
        }
        __syncthreads();

        // S = Q K^T for this thread's 4x4 block
        float s[4][4];
#pragma unroll
        for (int i = 0; i < 4; ++i)
#pragma unroll
            for (int j = 0; j < 4; ++j) s[i][j] = 0.f;

#pragma unroll 8
        for (int d = 0; d < 64; ++d) {
            const float4 qv = *reinterpret_cast<const float4*>(&Qs[d][ty * 4]);
            const float4 kv = *reinterpret_cast<const float4*>(&Ks[d][tx * 4]);
            const float qa[4] = {qv.x, qv.y, qv.z, qv.w};
            const float kb[4] = {kv.x, kv.y, kv.z, kv.w};
#pragma unroll
            for (int i = 0; i < 4; ++i)
#pragma unroll
                for (int j = 0; j < 4; ++j)
                    s[i][j] = fmaf(qa[i], kb[j], s[i][j]);
        }

        // scale + causal mask (only diagonal tile needs masking; q0==k0 there)
        const float sc = 0.125f;   // 1/sqrt(64)
        if (kt == qt) {
#pragma unroll
            for (int i = 0; i < 4; ++i)
#pragma unroll
                for (int j = 0; j < 4; ++j)
                    s[i][j] = (tx * 4 + j <= ty * 4 + i) ? s[i][j] * sc : -1e30f;
        } else {
#pragma unroll
            for (int i = 0; i < 4; ++i)
#pragma unroll
                for (int j = 0; j < 4; ++j) s[i][j] *= sc;
        }

        // online softmax: row stats across the 16 lanes sharing this row
        float pr[4][4];
#pragma unroll
        for (int i = 0; i < 4; ++i) {
            float rm = fmaxf(fmaxf(s[i][0], s[i][1]), fmaxf(s[i][2], s[i][3]));
            rm = fmaxf(rm, __shfl_xor(rm, 1));
            rm = fmaxf(rm, __shfl_xor(rm, 2));
            rm = fmaxf(rm, __shfl_xor(rm, 4));
            rm = fmaxf(rm, __shfl_xor(rm, 8));
            const float mnew = fmaxf(m_i[i], rm);
            const float corr = __expf(m_i[i] - mnew);
            float rs = 0.f;
#pragma unroll
            for (int j = 0; j < 4; ++j) {
                pr[i][j] = __expf(s[i][j] - mnew);
                rs += pr[i][j];
            }
            rs += __shfl_xor(rs, 1);
            rs += __shfl_xor(rs, 2);
            rs += __shfl_xor(rs, 4);
            rs += __shfl_xor(rs, 8);
            l_i[i] = l_i[i] * corr + rs;
            m_i[i] = mnew;
#pragma unroll
            for (int j = 0; j < 4; ++j) acc[i][j] *= corr;
        }

        // store P tile: Ps[r][j]
#pragma unroll
        for (int i = 0; i < 4; ++i) {
            float4 pv;
            pv.x = pr[i][0]; pv.y = pr[i][1]; pv.z = pr[i][2]; pv.w = pr[i][3];
            *reinterpret_cast<float4*>(&Ps[ty * 4 + i][tx * 4]) = pv;
        }
        __syncthreads();

        // O += P @ V  (this thread: rows ty*4..+3, dims tx*4..+3)
#pragma unroll 8
        for (int j = 0; j < 64; ++j) {
            const float4 vv = *reinterpret_cast<const float4*>(&Vs[j][tx * 4]);
            const float p0 = Ps[ty * 4 + 0][j];
            const float p1 = Ps[ty * 4 + 1][j];
            const float p2 = Ps[ty * 4 + 2][j];
            const float p3 = Ps[ty * 4 + 3][j];
            acc[0][0] = fmaf(p0, vv.x, acc[0][0]);
            acc[0][1] = fmaf(p0, vv.y, acc[0][1]);
            acc[0][2] = fmaf(p0, vv.z, acc[0][2]);
            acc[0][3] = fmaf(p0, vv.w, acc[0][3]);
            acc[1][0] = fmaf(p1, vv.x, acc[1][0]);
            acc[1][1] = fmaf(p1, vv.y, acc[1][1]);
            acc[1][2] = fmaf(p1, vv.z, acc[1][2]);
            acc[1][3] = fmaf(p1, vv.w, acc[1][3]);
            acc[2][0] = fmaf(p2, vv.x, acc[2][0]);
            acc[2][1] = fmaf(p2, vv.y, acc[2][1]);
            acc[2][2] = fmaf(p2, vv.z, acc[2][2]);
            acc[2][3] = fmaf(p2, vv.w, acc[2][3]);
            acc[3][0] = fmaf(p3, vv.x, acc[3][0]);
            acc[3][1] = fmaf(p3, vv.y, acc[3][1]);
            acc[3][2] = fmaf(p3, vv.z, acc[3][2]);
            acc[3][3] = fmaf(p3, vv.w, acc[3][3]);
        }
    }

    // normalize and store O in [B,T,C] layout (head h occupies cols h*64..+63)
#pragma unroll
    for (int i = 0; i < 4; ++i) {
        const float inv = 1.f / l_i[i];
        float4 o;
        o.x = acc[i][0] * inv;
        o.y = acc[i][1] * inv;
        o.z = acc[i][2] * inv;
        o.w = acc[i][3] * inv;
        *reinterpret_cast<float4*>(
            &O[(size_t)(b * GT_SEQ + q0 + ty * 4 + i) * GC + h * GDH + tx * 4]) = o;
    }
}

extern "C" void kernel_launch(void* const* d_in, const int* in_sizes, int n_in,
                              void* d_out, int out_size, void* d_ws, size_t ws_size,
                              hipStream_t stream) {
    (void)in_sizes; (void)n_in; (void)out_size; (void)ws_size;
    const float* x      = (const float*)d_in[0];   // [B,T,C]
    const float* w_attn = (const float*)d_in[1];   // [3C,C]
    const float* b_attn = (const float*)d_in[2];   // [3C]
    const float* w_proj = (const float*)d_in[3];   // [C,C]
    const float* b_proj = (const float*)d_in[4];   // [C]
    float* out = (float*)d_out;                    // [B,T,C]

    float* qkv    = (float*)d_ws;                        // [4096][3072] fp32
    float* attn_o = qkv + (size_t)GM * (3 * GC);         // [4096][1024] fp32

    dim3 blk(256);

    // 1) qkv = x @ w_attn^T + b_attn
    gemm_bt_bias<<<dim3((3 * GC) / GT, GM / GT), blk, 0, stream>>>(
        x, w_attn, b_attn, qkv, GM, 3 * GC, GC);

    // 2) causal flash attention -> attn_o in [B,T,C]
    flash_attn<<<dim3(GT_SEQ / 64, GB * GH), blk, 0, stream>>>(qkv, attn_o);

    // 3) out = attn_o @ w_proj^T + b_proj
    gemm_bt_bias<<<dim3(GC / GT, GM / GT), blk, 0, stream>>>(
        attn_o, w_proj, b_proj, out, GM, GC, GC);
}

// Round 2
// 590.535 us; speedup vs baseline: 1.6336x; 1.6336x over previous
//
#include <hip/hip_runtime.h>
#include <math.h>

// Problem constants: B=2, T=2048, C=1024, H=16, Dh=64
#define GB 2
#define GT_SEQ 2048
#define GC 1024
#define GH 16
#define GDH 64
#define GM (GB * GT_SEQ)      // 4096 rows

typedef __attribute__((ext_vector_type(8))) short bf16x8;   // 8 bf16 = 4 VGPRs
typedef __attribute__((ext_vector_type(4))) float f32x4;

__device__ __forceinline__ unsigned short f2bf(float f) {   // RNE f32 -> bf16
    unsigned int u = __float_as_uint(f);
    u += 0x7FFFu + ((u >> 16) & 1u);
    return (unsigned short)(u >> 16);
}
__device__ __forceinline__ float bf2f(unsigned short u) {   // exact bf16 -> f32
    return __uint_as_float(((unsigned int)u) << 16);
}

// async global->LDS, 16B per lane; LDS dest must be wave-uniform base (+lane*16 by HW)
#define GLOAD_LDS16(g, l) __builtin_amdgcn_global_load_lds( \
    (const __attribute__((address_space(1))) void*)(g),      \
    (__attribute__((address_space(3))) void*)(l), 16, 0, 0)

// ---------------- cast f32 -> bf16 (vectorized elementwise) ----------------
__global__ __launch_bounds__(256) void cast_f32_bf16(
    const float* __restrict__ in, unsigned short* __restrict__ out, int n)
{
    const int i = (blockIdx.x * 256 + threadIdx.x) * 4;
    if (i + 3 < n) {
        const float4 v = *reinterpret_cast<const float4*>(&in[i]);
        ushort4 o;
        o.x = f2bf(v.x); o.y = f2bf(v.y); o.z = f2bf(v.z); o.w = f2bf(v.w);
        *reinterpret_cast<ushort4*>(&out[i]) = o;
    }
}

// ---------------- bf16 MFMA GEMM: C[M][N] = A[M][K] @ B[N][K]^T + bias ----------------
// m97 pattern: 128x128 tile, BK=64, 4 waves (2x2 of 64x64), 16x16x32 MFMA,
// global_load_lds width=16, XOR-swizzled LDS ((row&7) on 16B chunk index).
__device__ __forceinline__ bf16x8 frag_ld(const char* base, int r, int kch) {
    return *reinterpret_cast<const bf16x8*>(base + r * 128 + ((kch ^ (r & 7)) << 4));
}

__global__ __launch_bounds__(256) void gemm_mfma_bt(
    const unsigned short* __restrict__ A,   // [M][K] bf16
    const unsigned short* __restrict__ B,   // [N][K] bf16
    const float* __restrict__ bias,         // [N] f32
    float* __restrict__ Cf,                 // f32 out (or null)
    unsigned short* __restrict__ Cb,        // bf16 out (or null)
    int M, int N, int K)
{
    __shared__ char As[128 * 128];   // 128 rows x 64 bf16 (128B), swizzled content
    __shared__ char Bs[128 * 128];

    const int tid  = threadIdx.x;
    const int lane = tid & 63;
    const int w    = tid >> 6;       // wave 0..3
    const int wm   = w >> 1;         // wave row (2)
    const int wn   = w & 1;          // wave col (2)
    const int m0 = blockIdx.y * 128;
    const int n0 = blockIdx.x * 128;

    f32x4 acc[4][4];
#pragma unroll
    for (int i = 0; i < 4; ++i)
#pragma unroll
        for (int j = 0; j < 4; ++j) acc[i][j] = (f32x4){0.f, 0.f, 0.f, 0.f};

    const int wbase = (tid & ~63);   // wave-uniform lane-block base

    for (int k0 = 0; k0 < K; k0 += 64) {
        // stage A,B tiles: linear chunk c -> (row=c>>3, chunk-in-row=c&7);
        // source pre-swizzled (cin ^ (row&7)) so swizzled READS see correct data.
        const char* Ag = (const char*)(A + (size_t)m0 * K + k0);
        const char* Bg = (const char*)(B + (size_t)n0 * K + k0);
#pragma unroll
        for (int i = 0; i < 4; ++i) {
            const int c = i * 256 + tid;
            const int row = c >> 3, cin = c & 7;
            const size_t goff = (size_t)row * (K * 2) + (size_t)((cin ^ (row & 7)) << 4);
            GLOAD_LDS16(Ag + goff, As + (i * 256 + wbase) * 16);
            GLOAD_LDS16(Bg + goff, Bs + (i * 256 + wbase) * 16);
        }
        __syncthreads();   // drains vmcnt(0) then barrier

#pragma unroll
        for (int ks = 0; ks < 2; ++ks) {
            const int kch = ks * 4 + (lane >> 4);
            bf16x8 a[4], b[4];
#pragma unroll
            for (int mi = 0; mi < 4; ++mi)
                a[mi] = frag_ld(As, wm * 64 + mi * 16 + (lane & 15), kch);
#pragma unroll
            for (int ni = 0; ni < 4; ++ni)
                b[ni] = frag_ld(Bs, wn * 64 + ni * 16 + (lane & 15), kch);
#pragma unroll
            for (int mi = 0; mi < 4; ++mi)
#pragma unroll
                for (int ni = 0; ni < 4; ++ni)
                    acc[mi][ni] = __builtin_amdgcn_mfma_f32_16x16x32_bf16(
                        a[mi], b[ni], acc[mi][ni], 0, 0, 0);
        }
        __syncthreads();   // all reads done before next stage overwrites
    }

    // epilogue: D layout col=lane&15, row=(lane>>4)*4+j  [m89-verified]
    const int lc  = lane & 15;
    const int lr4 = (lane >> 4) * 4;
#pragma unroll
    for (int ni = 0; ni < 4; ++ni) {
        const int gcol = n0 + wn * 64 + ni * 16 + lc;
        const float bv = bias[gcol];
#pragma unroll
        for (int mi = 0; mi < 4; ++mi) {
            const int grow0 = m0 + wm * 64 + mi * 16 + lr4;
#pragma unroll
            for (int j = 0; j < 4; ++j) {
                const float v = acc[mi][ni][j] + bv;
                if (Cb) Cb[(size_t)(grow0 + j) * N + gcol] = f2bf(v);
                else    Cf[(size_t)(grow0 + j) * N + gcol] = v;
            }
        }
    }
}

// ---------------- Flash attention (causal, online softmax, fp32 math, bf16 I/O) ----------------
#define ASTR 68

__global__ __launch_bounds__(256) void flash_attn(
    const unsigned short* __restrict__ qkv,   // [B*T][3C] bf16: q | k | v
    unsigned short* __restrict__ O)           // [B*T][C] bf16
{
    __shared__ float Qs[64][ASTR];   // [d][r]
    __shared__ float Ks[64][ASTR];   // [d][c]
    __shared__ float Vs[64][ASTR];   // [j][d]
    __shared__ float Ps[64][ASTR];   // [r][j]

    const int tid = threadIdx.x;
    const int tx = tid & 15;
    const int ty = tid >> 4;
    const int qt = blockIdx.x;
    const int bh = blockIdx.y;
    const int b  = bh >> 4;
    const int h  = bh & 15;
    const int q0 = qt * 64;

    const int ld = (tid & 15) * 4;
    const int lr = tid >> 4;

#pragma unroll
    for (int p = 0; p < 4; ++p) {
        const int r = lr + p * 16;
        const ushort4 v = *reinterpret_cast<const ushort4*>(
            &qkv[(size_t)(b * GT_SEQ + q0 + r) * (3 * GC) + h * GDH + ld]);
        Qs[ld + 0][r] = bf2f(v.x);
        Qs[ld + 1][r] = bf2f(v.y);
        Qs[ld + 2][r] = bf2f(v.z);
        Qs[ld + 3][r] = bf2f(v.w);
    }

    float m_i[4], l_i[4], acc[4][4];
#pragma unroll
    for (int i = 0; i < 4; ++i) {
        m_i[i] = -1e30f;
        l_i[i] = 0.f;
#pragma unroll
        for (int j = 0; j < 4; ++j) acc[i][j] = 0.f;
    }

    for (int kt = 0; kt <= qt; ++kt) {
        const int k0 = kt * 64;
        __syncthreads();

#pragma unroll
        for (int p = 0; p < 4; ++p) {
            const int r = lr + p * 16;
            const size_t base = (size_t)(b * GT_SEQ + k0 + r) * (3 * GC) + h * GDH + ld;
            const ushort4 kv = *reinterpret_cast<const ushort4*>(&qkv[base + GC]);
            Ks[ld + 0][r] = bf2f(kv.x);
            Ks[ld + 1][r] = bf2f(kv.y);
            Ks[ld + 2][r] = bf2f(kv.z);
            Ks[ld + 3][r] = bf2f(kv.w);
            const ushort4 vv = *reinterpret_cast<const ushort4*>(&qkv[base + 2 * GC]);
            Vs[r][ld + 0] = bf2f(vv.x);
            Vs[r][ld + 1] = bf2f(vv.y);
            Vs[r][ld + 2] = bf2f(vv.z);
            Vs[r][ld + 3] = bf2f(vv.w);
        }
        __syncthreads();

        float s[4][4];
#pragma unroll
        for (int i = 0; i < 4; ++i)
#pragma unroll
            for (int j = 0; j < 4; ++j) s[i][j] = 0.f;

#pragma unroll 8
        for (int d = 0; d < 64; ++d) {
            const float4 qv = *reinterpret_cast<const float4*>(&Qs[d][ty * 4]);
            const float4 kv = *reinterpret_cast<const float4*>(&Ks[d][tx * 4]);
            const float qa[4] = {qv.x, qv.y, qv.z, qv.w};
            const float kb[4] = {kv.x, kv.y, kv.z, kv.w};
#pragma unroll
            for (int i = 0; i < 4; ++i)
#pragma unroll
                for (int j = 0; j < 4; ++j)
                    s[i][j] = fmaf(qa[i], kb[j], s[i][j]);
        }

        const float sc = 0.125f;
        if (kt == qt) {
#pragma unroll
            for (int i = 0; i < 4; ++i)
#pragma unroll
                for (int j = 0; j < 4; ++j)
                    s[i][j] = (tx * 4 + j <= ty * 4 + i) ? s[i][j] * sc : -1e30f;
        } else {
#pragma unroll
            for (int i = 0; i < 4; ++i)
#pragma unroll
                for (int j = 0; j < 4; ++j) s[i][j] *= sc;
        }

        float pr[4][4];
#pragma unroll
        for (int i = 0; i < 4; ++i) {
            float rm = fmaxf(fmaxf(s[i][0], s[i][1]), fmaxf(s[i][2], s[i][3]));
            rm = fmaxf(rm, __shfl_xor(rm, 1));
            rm = fmaxf(rm, __shfl_xor(rm, 2));
            rm = fmaxf(rm, __shfl_xor(rm, 4));
            rm = fmaxf(rm, __shfl_xor(rm, 8));
            const float mnew = fmaxf(m_i[i], rm);
            const float corr = __expf(m_i[i] - mnew);
            float rs = 0.f;
#pragma unroll
            for (int j = 0; j < 4; ++j) {
                pr[i][j] = __expf(s[i][j] - mnew);
                rs += pr[i][j];
            }
            rs += __shfl_xor(rs, 1);
            rs += __shfl_xor(rs, 2);
            rs += __shfl_xor(rs, 4);
            rs += __shfl_xor(rs, 8);
            l_i[i] = l_i[i] * corr + rs;
            m_i[i] = mnew;
#pragma unroll
            for (int j = 0; j < 4; ++j) acc[i][j] *= corr;
        }

#pragma unroll
        for (int i = 0; i < 4; ++i) {
            float4 pv;
            pv.x = pr[i][0]; pv.y = pr[i][1]; pv.z = pr[i][2]; pv.w = pr[i][3];
            *reinterpret_cast<float4*>(&Ps[ty * 4 + i][tx * 4]) = pv;
        }
        __syncthreads();

#pragma unroll 8
        for (int j = 0; j < 64; ++j) {
            const float4 vv = *reinterpret_cast<const float4*>(&Vs[j][tx * 4]);
            const float p0 = Ps[ty * 4 + 0][j];
            const float p1 = Ps[ty * 4 + 1][j];
            const float p2 = Ps[ty * 4 + 2][j];
            const float p3 = Ps[ty * 4 + 3][j];
            acc[0][0] = fmaf(p0, vv.x, acc[0][0]);
            acc[0][1] = fmaf(p0, vv.y, acc[0][1]);
            acc[0][2] = fmaf(p0, vv.z, acc[0][2]);
            acc[0][3] = fmaf(p0, vv.w, acc[0][3]);
            acc[1][0] = fmaf(p1, vv.x, acc[1][0]);
            acc[1][1] = fmaf(p1, vv.y, acc[1][1]);
            acc[1][2] = fmaf(p1, vv.z, acc[1][2]);
            acc[1][3] = fmaf(p1, vv.w, acc[1][3]);
            acc[2][0] = fmaf(p2, vv.x, acc[2][0]);
            acc[2][1] = fmaf(p2, vv.y, acc[2][1]);
            acc[2][2] = fmaf(p2, vv.z, acc[2][2]);
            acc[2][3] = fmaf(p2, vv.w, acc[2][3]);
            acc[3][0] = fmaf(p3, vv.x, acc[3][0]);
            acc[3][1] = fmaf(p3, vv.y, acc[3][1]);
            acc[3][2] = fmaf(p3, vv.z, acc[3][2]);
            acc[3][3] = fmaf(p3, vv.w, acc[3][3]);
        }
    }

#pragma unroll
    for (int i = 0; i < 4; ++i) {
        const float inv = 1.f / l_i[i];
        ushort4 o;
        o.x = f2bf(acc[i][0] * inv);
        o.y = f2bf(acc[i][1] * inv);
        o.z = f2bf(acc[i][2] * inv);
        o.w = f2bf(acc[i][3] * inv);
        *reinterpret_cast<ushort4*>(
            &O[(size_t)(b * GT_SEQ + q0 + ty * 4 + i) * GC + h * GDH + tx * 4]) = o;
    }
}

extern "C" void kernel_launch(void* const* d_in, const int* in_sizes, int n_in,
                              void* d_out, int out_size, void* d_ws, size_t ws_size,
                              hipStream_t stream) {
    (void)in_sizes; (void)n_in; (void)out_size; (void)ws_size;
    const float* x      = (const float*)d_in[0];   // [B,T,C]
    const float* w_attn = (const float*)d_in[1];   // [3C,C]
    const float* b_attn = (const float*)d_in[2];   // [3C]
    const float* w_proj = (const float*)d_in[3];   // [C,C]
    const float* b_proj = (const float*)d_in[4];   // [C]
    float* out = (float*)d_out;                    // [B,T,C] f32

    unsigned short* xb   = (unsigned short*)d_ws;            // [4096][1024] bf16
    unsigned short* wab  = xb   + (size_t)GM * GC;           // [3072][1024] bf16
    unsigned short* wpb  = wab  + (size_t)3 * GC * GC;       // [1024][1024] bf16
    unsigned short* qkvb = wpb  + (size_t)GC * GC;           // [4096][3072] bf16
    unsigned short* aob  = qkvb + (size_t)GM * 3 * GC;       // [4096][1024] bf16
    // total ws use: 48 MB

    // casts (exact grids: n divisible by 1024)
    cast_f32_bf16<<<dim3(4096), dim3(256), 0, stream>>>(x,      xb,  GM * GC);
    cast_f32_bf16<<<dim3(3072), dim3(256), 0, stream>>>(w_attn, wab, 3 * GC * GC);
    cast_f32_bf16<<<dim3(1024), dim3(256), 0, stream>>>(w_proj, wpb, GC * GC);

    // 1) qkv = x @ w_attn^T + b_attn   (bf16 out)
    gemm_mfma_bt<<<dim3(3 * GC / 128, GM / 128), dim3(256), 0, stream>>>(
        xb, wab, b_attn, nullptr, qkvb, GM, 3 * GC, GC);

    // 2) causal flash attention -> aob bf16 [B,T,C]
    flash_attn<<<dim3(GT_SEQ / 64, GB * GH), dim3(256), 0, stream>>>(qkvb, aob);

    // 3) out = aob @ w_proj^T + b_proj (f32 out)
    gemm_mfma_bt<<<dim3(GC / 128, GM / 128), dim3(256), 0, stream>>>(
        aob, wpb, b_proj, out, nullptr, GM, GC, GC);
}

// Round 3
// 209.598 us; speedup vs baseline: 4.6026x; 2.8175x over previous
//
#include <hip/hip_runtime.h>
#include <math.h>

// Problem constants: B=2, T=2048, C=1024, H=16, Dh=64
#define GB 2
#define GT_SEQ 2048
#define GC 1024
#define GH 16
#define GDH 64
#define GM (GB * GT_SEQ)      // 4096 rows

typedef __attribute__((ext_vector_type(8))) short bf16x8;   // 8 bf16 = 4 VGPRs
typedef __attribute__((ext_vector_type(4))) float f32x4;

__device__ __forceinline__ unsigned short f2bf(float f) {   // RNE f32 -> bf16
    unsigned int u = __float_as_uint(f);
    u += 0x7FFFu + ((u >> 16) & 1u);
    return (unsigned short)(u >> 16);
}
__device__ __forceinline__ float bf2f(unsigned short u) {   // exact bf16 -> f32
    return __uint_as_float(((unsigned int)u) << 16);
}

// async global->LDS, 16B per lane; LDS dest is wave-uniform base (+lane*16 by HW)
#define GLOAD_LDS16(g, l) __builtin_amdgcn_global_load_lds( \
    (const __attribute__((address_space(1))) void*)(g),      \
    (__attribute__((address_space(3))) void*)(l), 16, 0, 0)

// swizzled fragment read: rows of 64 bf16 (128B = 8 chunks), chunk ^= (row&7)
__device__ __forceinline__ bf16x8 frag_ld(const char* base, int r, int kch) {
    return *reinterpret_cast<const bf16x8*>(base + r * 128 + ((kch ^ (r & 7)) << 4));
}

// ---------------- cast f32 -> bf16 ----------------
__global__ __launch_bounds__(256) void cast_f32_bf16(
    const float* __restrict__ in, unsigned short* __restrict__ out, int n)
{
    const int i = (blockIdx.x * 256 + threadIdx.x) * 4;
    if (i + 3 < n) {
        const float4 v = *reinterpret_cast<const float4*>(&in[i]);
        ushort4 o;
        o.x = f2bf(v.x); o.y = f2bf(v.y); o.z = f2bf(v.z); o.w = f2bf(v.w);
        *reinterpret_cast<ushort4*>(&out[i]) = o;
    }
}

// ---------------- bf16 MFMA GEMM: C = A @ B^T + bias (validated round 2) ----------------
__global__ __launch_bounds__(256) void gemm_mfma_bt(
    const unsigned short* __restrict__ A,   // [M][K] bf16
    const unsigned short* __restrict__ B,   // [N][K] bf16
    const float* __restrict__ bias,         // [N] f32
    float* __restrict__ Cf,                 // f32 out (or null)
    unsigned short* __restrict__ Cb,        // bf16 out (or null)
    int M, int N, int K)
{
    __shared__ char As[128 * 128];
    __shared__ char Bs[128 * 128];

    const int tid  = threadIdx.x;
    const int lane = tid & 63;
    const int w    = tid >> 6;
    const int wm   = w >> 1;
    const int wn   = w & 1;
    const int m0 = blockIdx.y * 128;
    const int n0 = blockIdx.x * 128;

    f32x4 acc[4][4];
#pragma unroll
    for (int i = 0; i < 4; ++i)
#pragma unroll
        for (int j = 0; j < 4; ++j) acc[i][j] = (f32x4){0.f, 0.f, 0.f, 0.f};

    const int wbase = (tid & ~63);

    for (int k0 = 0; k0 < K; k0 += 64) {
        const char* Ag = (const char*)(A + (size_t)m0 * K + k0);
        const char* Bg = (const char*)(B + (size_t)n0 * K + k0);
#pragma unroll
        for (int i = 0; i < 4; ++i) {
            const int c = i * 256 + tid;
            const int row = c >> 3, cin = c & 7;
            const size_t goff = (size_t)row * (K * 2) + (size_t)((cin ^ (row & 7)) << 4);
            GLOAD_LDS16(Ag + goff, As + (i * 256 + wbase) * 16);
            GLOAD_LDS16(Bg + goff, Bs + (i * 256 + wbase) * 16);
        }
        __syncthreads();

#pragma unroll
        for (int ks = 0; ks < 2; ++ks) {
            const int kch = ks * 4 + (lane >> 4);
            bf16x8 a[4], b[4];
#pragma unroll
            for (int mi = 0; mi < 4; ++mi)
                a[mi] = frag_ld(As, wm * 64 + mi * 16 + (lane & 15), kch);
#pragma unroll
            for (int ni = 0; ni < 4; ++ni)
                b[ni] = frag_ld(Bs, wn * 64 + ni * 16 + (lane & 15), kch);
#pragma unroll
            for (int mi = 0; mi < 4; ++mi)
#pragma unroll
                for (int ni = 0; ni < 4; ++ni)
                    acc[mi][ni] = __builtin_amdgcn_mfma_f32_16x16x32_bf16(
                        a[mi], b[ni], acc[mi][ni], 0, 0, 0);
        }
        __syncthreads();
    }

    const int lc  = lane & 15;
    const int lr4 = (lane >> 4) * 4;
#pragma unroll
    for (int ni = 0; ni < 4; ++ni) {
        const int gcol = n0 + wn * 64 + ni * 16 + lc;
        const float bv = bias[gcol];
#pragma unroll
        for (int mi = 0; mi < 4; ++mi) {
            const int grow0 = m0 + wm * 64 + mi * 16 + lr4;
#pragma unroll
            for (int j = 0; j < 4; ++j) {
                const float v = acc[mi][ni][j] + bv;
                if (Cb) Cb[(size_t)(grow0 + j) * N + gcol] = f2bf(v);
                else    Cf[(size_t)(grow0 + j) * N + gcol] = v;
            }
        }
    }
}

// ---------------- MFMA flash attention (causal, online softmax) ----------------
// Block: 4 waves, one (b, h, 128-row Q tile); wave w owns rows w*32..+31.
// K/V tiles of 64. Q in registers (pre-scaled). K staged via global_load_lds
// (pre-swizzled source); V staged transposed via regs; P bf16 in wave-private LDS.
__global__ __launch_bounds__(256) void flash_attn_mfma(
    const unsigned short* __restrict__ qkv,   // [B*T][3C] bf16: q | k | v
    unsigned short* __restrict__ O)           // [B*T][C] bf16
{
    __shared__ char Ks[64 * 128];    // 64 keys x 64 bf16, swizzled
    __shared__ char Vt[64 * 128];    // 64 d-rows x 64 keys bf16, swizzled
    __shared__ char Ps[128 * 128];   // 128 q-rows x 64 keys bf16, swizzled

    const int tid  = threadIdx.x;
    const int lane = tid & 63;
    const int w    = tid >> 6;
    const int l15  = lane & 15;
    const int l4   = lane >> 4;
    const int qt   = (int)(gridDim.x - 1) - (int)blockIdx.x;   // heavy tiles first
    const int bh   = blockIdx.y;
    const int b    = bh >> 4;
    const int h    = bh & 15;
    const int q0   = qt * 128;
    const int q0w  = q0 + w * 32;
    const int wbase = tid & ~63;

    // Q fragments (2 m-frags x 2 k-steps), pre-scaled by 1/sqrt(64)=0.125 (exact in bf16)
    bf16x8 qf[2][2];
#pragma unroll
    for (int mi = 0; mi < 2; ++mi)
#pragma unroll
        for (int s = 0; s < 2; ++s) {
            const size_t off = (size_t)(b * GT_SEQ + q0w + mi * 16 + l15) * (3 * GC)
                             + h * GDH + s * 32 + l4 * 8;
            bf16x8 v = *reinterpret_cast<const bf16x8*>(qkv + off);
#pragma unroll
            for (int e = 0; e < 8; ++e)
                v[e] = (short)f2bf(bf2f((unsigned short)v[e]) * 0.125f);
            qf[mi][s] = v;
        }

    f32x4 acc_o[2][4];
    float m_r[2][4], l_r[2][4];
#pragma unroll
    for (int mi = 0; mi < 2; ++mi)
#pragma unroll
        for (int j = 0; j < 4; ++j) {
            m_r[mi][j] = -1e30f;
            l_r[mi][j] = 0.f;
        }
#pragma unroll
    for (int mi = 0; mi < 2; ++mi)
#pragma unroll
        for (int nd = 0; nd < 4; ++nd) acc_o[mi][nd] = (f32x4){0.f, 0.f, 0.f, 0.f};

    const int ntiles = qt * 2 + 2;

    for (int kt = 0; kt < ntiles; ++kt) {
        const int k0 = kt * 64;
        __syncthreads();   // previous tile's K/V reads complete

        // stage K tile (swizzled source -> linear LDS dest)
        const size_t kbase = ((size_t)(b * GT_SEQ + k0) * (3 * GC) + GC + h * GDH) * 2;
#pragma unroll
        for (int i = 0; i < 2; ++i) {
            const int c = i * 256 + tid;
            const int row = c >> 3, cin = c & 7;
            const size_t goff = kbase + (size_t)row * (3 * GC * 2)
                              + (size_t)((cin ^ (row & 7)) << 4);
            GLOAD_LDS16((const char*)qkv + goff, Ks + (i * 256 + wbase) * 16);
        }
        // stage V transposed: Vt[d][k], swizzled
#pragma unroll
        for (int i = 0; i < 4; ++i) {
            const int k  = i * 16 + (tid >> 4);
            const int d0 = (tid & 15) * 4;
            const ushort4 vv = *reinterpret_cast<const ushort4*>(
                qkv + (size_t)(b * GT_SEQ + k0 + k) * (3 * GC) + 2 * GC + h * GDH + d0);
            const unsigned short vs[4] = {vv.x, vv.y, vv.z, vv.w};
#pragma unroll
            for (int e = 0; e < 4; ++e) {
                const int d = d0 + e;
                *(unsigned short*)(Vt + d * 128 + ((((k >> 3) ^ (d & 7))) << 4) + (k & 7) * 2) = vs[e];
            }
        }
        __syncthreads();   // staging visible (vmcnt/lgkm drained by barrier)

        if (k0 <= q0w + 31) {   // wave-uniform: skip fully-masked tiles
            // ---- QK^T: S[32 q][64 k] ----
            f32x4 s_acc[2][4];
#pragma unroll
            for (int mi = 0; mi < 2; ++mi)
#pragma unroll
                for (int ni = 0; ni < 4; ++ni) s_acc[mi][ni] = (f32x4){0.f, 0.f, 0.f, 0.f};
#pragma unroll
            for (int s = 0; s < 2; ++s) {
                bf16x8 kf[4];
#pragma unroll
                for (int ni = 0; ni < 4; ++ni)
                    kf[ni] = frag_ld(Ks, ni * 16 + l15, s * 4 + l4);
#pragma unroll
                for (int mi = 0; mi < 2; ++mi)
#pragma unroll
                    for (int ni = 0; ni < 4; ++ni)
                        s_acc[mi][ni] = __builtin_amdgcn_mfma_f32_16x16x32_bf16(
                            qf[mi][s], kf[ni], s_acc[mi][ni], 0, 0, 0);
            }

            // ---- causal mask (D layout: col=l15 within frag, row=l4*4+j) ----
            if (k0 + 63 > q0w) {
#pragma unroll
                for (int mi = 0; mi < 2; ++mi)
#pragma unroll
                    for (int ni = 0; ni < 4; ++ni)
#pragma unroll
                        for (int j = 0; j < 4; ++j)
                            if (k0 + ni * 16 + l15 > q0w + mi * 16 + l4 * 4 + j)
                                s_acc[mi][ni][j] = -1e30f;
            }

            // ---- online softmax + P write (wave-private LDS rows) ----
#pragma unroll
            for (int mi = 0; mi < 2; ++mi)
#pragma unroll
                for (int j = 0; j < 4; ++j) {
                    float rm = fmaxf(fmaxf(s_acc[mi][0][j], s_acc[mi][1][j]),
                                     fmaxf(s_acc[mi][2][j], s_acc[mi][3][j]));
                    rm = fmaxf(rm, __shfl_xor(rm, 1));
                    rm = fmaxf(rm, __shfl_xor(rm, 2));
                    rm = fmaxf(rm, __shfl_xor(rm, 4));
                    rm = fmaxf(rm, __shfl_xor(rm, 8));
                    const float mnew = fmaxf(m_r[mi][j], rm);
                    const float corr = __expf(m_r[mi][j] - mnew);
                    m_r[mi][j] = mnew;
                    const int prow  = w * 32 + mi * 16 + l4 * 4 + j;
                    const int pbase = prow * 128;
                    const int psw   = prow & 7;
                    float rs = 0.f;
#pragma unroll
                    for (int ni = 0; ni < 4; ++ni) {
                        const float p = __expf(s_acc[mi][ni][j] - mnew);
                        rs += p;
                        const int kcol = ni * 16 + l15;
                        *(unsigned short*)(Ps + pbase + (((kcol >> 3) ^ psw) << 4)
                                           + (kcol & 7) * 2) = f2bf(p);
                    }
                    rs += __shfl_xor(rs, 1);
                    rs += __shfl_xor(rs, 2);
                    rs += __shfl_xor(rs, 4);
                    rs += __shfl_xor(rs, 8);
                    l_r[mi][j] = l_r[mi][j] * corr + rs;
#pragma unroll
                    for (int nd = 0; nd < 4; ++nd) acc_o[mi][nd][j] *= corr;
                }

            // ---- PV: O[32 q][64 d] += P @ V  (DS ops in-order per wave) ----
#pragma unroll
            for (int s = 0; s < 2; ++s) {
                bf16x8 pa[2], vb[4];
#pragma unroll
                for (int mi = 0; mi < 2; ++mi)
                    pa[mi] = frag_ld(Ps, w * 32 + mi * 16 + l15, s * 4 + l4);
#pragma unroll
                for (int nd = 0; nd < 4; ++nd)
                    vb[nd] = frag_ld(Vt, nd * 16 + l15, s * 4 + l4);
#pragma unroll
                for (int mi = 0; mi < 2; ++mi)
#pragma unroll
                    for (int nd = 0; nd < 4; ++nd)
                        acc_o[mi][nd] = __builtin_amdgcn_mfma_f32_16x16x32_bf16(
                            pa[mi], vb[nd], acc_o[mi][nd], 0, 0, 0);
            }
        }
    }

    // ---- epilogue: normalize, store bf16 [B,T,C] ----
#pragma unroll
    for (int mi = 0; mi < 2; ++mi)
#pragma unroll
        for (int j = 0; j < 4; ++j) {
            const float inv = 1.f / l_r[mi][j];
            const size_t rbase = (size_t)(b * GT_SEQ + q0w + mi * 16 + l4 * 4 + j) * GC
                               + h * GDH + l15;
#pragma unroll
            for (int nd = 0; nd < 4; ++nd)
                O[rbase + nd * 16] = f2bf(acc_o[mi][nd][j] * inv);
        }
}

extern "C" void kernel_launch(void* const* d_in, const int* in_sizes, int n_in,
                              void* d_out, int out_size, void* d_ws, size_t ws_size,
                              hipStream_t stream) {
    (void)in_sizes; (void)n_in; (void)out_size; (void)ws_size;
    const float* x      = (const float*)d_in[0];
    const float* w_attn = (const float*)d_in[1];
    const float* b_attn = (const float*)d_in[2];
    const float* w_proj = (const float*)d_in[3];
    const float* b_proj = (const float*)d_in[4];
    float* out = (float*)d_out;

    unsigned short* xb   = (unsigned short*)d_ws;            // [4096][1024] bf16
    unsigned short* wab  = xb   + (size_t)GM * GC;           // [3072][1024] bf16
    unsigned short* wpb  = wab  + (size_t)3 * GC * GC;       // [1024][1024] bf16
    unsigned short* qkvb = wpb  + (size_t)GC * GC;           // [4096][3072] bf16
    unsigned short* aob  = qkvb + (size_t)GM * 3 * GC;       // [4096][1024] bf16

    cast_f32_bf16<<<dim3(4096), dim3(256), 0, stream>>>(x,      xb,  GM * GC);
    cast_f32_bf16<<<dim3(3072), dim3(256), 0, stream>>>(w_attn, wab, 3 * GC * GC);
    cast_f32_bf16<<<dim3(1024), dim3(256), 0, stream>>>(w_proj, wpb, GC * GC);

    gemm_mfma_bt<<<dim3(3 * GC / 128, GM / 128), dim3(256), 0, stream>>>(
        xb, wab, b_attn, nullptr, qkvb, GM, 3 * GC, GC);

    flash_attn_mfma<<<dim3(GT_SEQ / 128, GB * GH), dim3(256), 0, stream>>>(qkvb, aob);

    gemm_mfma_bt<<<dim3(GC / 128, GM / 128), dim3(256), 0, stream>>>(
        aob, wpb, b_proj, out, nullptr, GM, GC, GC);
}

// Round 5
// 168.057 us; speedup vs baseline: 5.7403x; 1.2472x over previous
//
#include <hip/hip_runtime.h>
#include <math.h>

// Problem constants: B=2, T=2048, C=1024, H=16, Dh=64
#define GB 2
#define GT_SEQ 2048
#define GC 1024
#define GH 16
#define GDH 64
#define GM (GB * GT_SEQ)      // 4096 rows

typedef __attribute__((ext_vector_type(8))) short bf16x8;   // 8 bf16 = 4 VGPRs
typedef __attribute__((ext_vector_type(8))) unsigned short u16x8;
typedef __attribute__((ext_vector_type(4))) float f32x4;

__device__ __forceinline__ unsigned short f2bf(float f) {   // RNE f32 -> bf16
    unsigned int u = __float_as_uint(f);
    u += 0x7FFFu + ((u >> 16) & 1u);
    return (unsigned short)(u >> 16);
}
__device__ __forceinline__ float bf2f(unsigned short u) {   // exact bf16 -> f32
    return __uint_as_float(((unsigned int)u) << 16);
}
// hardware 2^x (v_exp_f32); avoids glibc __exp2f macro collision
__device__ __forceinline__ float hw_exp2(float x) {
    return __builtin_amdgcn_exp2f(x);
}

// async global->LDS, 16B per lane; LDS dest is wave-uniform base (+lane*16 by HW)
#define GLOAD_LDS16(g, l) __builtin_amdgcn_global_load_lds( \
    (const __attribute__((address_space(1))) void*)(g),      \
    (__attribute__((address_space(3))) void*)(l), 16, 0, 0)

// swizzled fragment read: rows of 64 bf16 (128B = 8 chunks), chunk ^= (row&7)
__device__ __forceinline__ bf16x8 frag_ld(const char* base, int r, int kch) {
    return *reinterpret_cast<const bf16x8*>(base + r * 128 + ((kch ^ (r & 7)) << 4));
}

// ---------------- cast f32 -> bf16 ----------------
__global__ __launch_bounds__(256) void cast_f32_bf16(
    const float* __restrict__ in, unsigned short* __restrict__ out, int n)
{
    const int i = (blockIdx.x * 256 + threadIdx.x) * 4;
    if (i + 3 < n) {
        const float4 v = *reinterpret_cast<const float4*>(&in[i]);
        ushort4 o;
        o.x = f2bf(v.x); o.y = f2bf(v.y); o.z = f2bf(v.z); o.w = f2bf(v.w);
        *reinterpret_cast<ushort4*>(&out[i]) = o;
    }
}

// ---------------- bf16 MFMA GEMM: C = A @ B^T + bias (validated rounds 2-3) ----------------
__global__ __launch_bounds__(256) void gemm_mfma_bt(
    const unsigned short* __restrict__ A,   // [M][K] bf16
    const unsigned short* __restrict__ B,   // [N][K] bf16
    const float* __restrict__ bias,         // [N] f32
    float* __restrict__ Cf,                 // f32 out (or null)
    unsigned short* __restrict__ Cb,        // bf16 out (or null)
    int M, int N, int K)
{
    __shared__ char As[128 * 128];
    __shared__ char Bs[128 * 128];

    const int tid  = threadIdx.x;
    const int lane = tid & 63;
    const int w    = tid >> 6;
    const int wm   = w >> 1;
    const int wn   = w & 1;
    const int m0 = blockIdx.y * 128;
    const int n0 = blockIdx.x * 128;

    f32x4 acc[4][4];
#pragma unroll
    for (int i = 0; i < 4; ++i)
#pragma unroll
        for (int j = 0; j < 4; ++j) acc[i][j] = (f32x4){0.f, 0.f, 0.f, 0.f};

    const int wbase = (tid & ~63);

    for (int k0 = 0; k0 < K; k0 += 64) {
        const char* Ag = (const char*)(A + (size_t)m0 * K + k0);
        const char* Bg = (const char*)(B + (size_t)n0 * K + k0);
#pragma unroll
        for (int i = 0; i < 4; ++i) {
            const int c = i * 256 + tid;
            const int row = c >> 3, cin = c & 7;
            const size_t goff = (size_t)row * (K * 2) + (size_t)((cin ^ (row & 7)) << 4);
            GLOAD_LDS16(Ag + goff, As + (i * 256 + wbase) * 16);
            GLOAD_LDS16(Bg + goff, Bs + (i * 256 + wbase) * 16);
        }
        __syncthreads();

#pragma unroll
        for (int ks = 0; ks < 2; ++ks) {
            const int kch = ks * 4 + (lane >> 4);
            bf16x8 a[4], b[4];
#pragma unroll
            for (int mi = 0; mi < 4; ++mi)
                a[mi] = frag_ld(As, wm * 64 + mi * 16 + (lane & 15), kch);
#pragma unroll
            for (int ni = 0; ni < 4; ++ni)
                b[ni] = frag_ld(Bs, wn * 64 + ni * 16 + (lane & 15), kch);
#pragma unroll
            for (int mi = 0; mi < 4; ++mi)
#pragma unroll
                for (int ni = 0; ni < 4; ++ni)
                    acc[mi][ni] = __builtin_amdgcn_mfma_f32_16x16x32_bf16(
                        a[mi], b[ni], acc[mi][ni], 0, 0, 0);
        }
        __syncthreads();
    }

    const int lc  = lane & 15;
    const int lr4 = (lane >> 4) * 4;
#pragma unroll
    for (int ni = 0; ni < 4; ++ni) {
        const int gcol = n0 + wn * 64 + ni * 16 + lc;
        const float bv = bias[gcol];
#pragma unroll
        for (int mi = 0; mi < 4; ++mi) {
            const int grow0 = m0 + wm * 64 + mi * 16 + lr4;
#pragma unroll
            for (int j = 0; j < 4; ++j) {
                const float v = acc[mi][ni][j] + bv;
                if (Cb) Cb[(size_t)(grow0 + j) * N + gcol] = f2bf(v);
                else    Cf[(size_t)(grow0 + j) * N + gcol] = v;
            }
        }
    }
}

// ---------------- rearrange qkv -> per-head Q (pre-scaled), K, V^T ----------------
// Qh/Kh: [bh][t][d] (rows of 64 bf16 = 128B);  Vt: [bh][d][t].
__global__ __launch_bounds__(256) void rearrange_qkv(
    const unsigned short* __restrict__ qkv,  // [4096][3072]
    unsigned short* __restrict__ Qh,
    unsigned short* __restrict__ Kh,
    unsigned short* __restrict__ Vt)
{
    __shared__ unsigned short vtile[64][72];   // [t][d], padded

    const int tid = threadIdx.x;
    const int tt  = blockIdx.x;     // t-tile 0..31
    const int bh  = blockIdx.y;     // 0..31
    const int b = bh >> 4, h = bh & 15;
    const int t0 = tt * 64;

    const size_t srow = (size_t)(b * GT_SEQ + t0) * (3 * GC) + h * GDH;
    const size_t drow = (size_t)bh * GT_SEQ * GDH + (size_t)t0 * GDH;

#pragma unroll
    for (int i = 0; i < 2; ++i) {
        const int c  = i * 256 + tid;      // 0..511
        const int tr = c >> 3, ch = c & 7; // row in tile, 16B chunk
        const size_t s = srow + (size_t)tr * (3 * GC) + ch * 8;
        // Q: scale by 0.125 (exact in bf16)
        u16x8 q = *reinterpret_cast<const u16x8*>(qkv + s);
        u16x8 qo;
#pragma unroll
        for (int e = 0; e < 8; ++e) qo[e] = f2bf(bf2f(q[e]) * 0.125f);
        *reinterpret_cast<u16x8*>(Qh + drow + tr * GDH + ch * 8) = qo;
        // K: straight copy
        *reinterpret_cast<u16x8*>(Kh + drow + tr * GDH + ch * 8) =
            *reinterpret_cast<const u16x8*>(qkv + s + GC);
        // V -> LDS tile
        *reinterpret_cast<u16x8*>(&vtile[tr][ch * 8]) =
            *reinterpret_cast<const u16x8*>(qkv + s + 2 * GC);
    }
    __syncthreads();

    // transposed writeout: Vt[bh][d][t0..t0+63]
#pragma unroll
    for (int i = 0; i < 2; ++i) {
        const int c  = i * 256 + tid;
        const int d  = c >> 3, ch = c & 7;   // d row, 8-t chunk
        u16x8 o;
#pragma unroll
        for (int e = 0; e < 8; ++e) o[e] = vtile[ch * 8 + e][d];
        *reinterpret_cast<u16x8*>(
            Vt + (size_t)bh * GDH * GT_SEQ + (size_t)d * GT_SEQ + t0 + ch * 8) = o;
    }
}

// ---------------- barrier-free MFMA flash attention ----------------
// One wave (64-thread block) per 32-row Q tile. K/V^T fragments direct from
// global (L2-resident). Only LDS use: wave-private 4KB P round-trip.
__global__ __launch_bounds__(64, 2) void flash_attn_mfma2(
    const unsigned short* __restrict__ Qh,   // [32][2048][64], pre-scaled by 0.125
    const unsigned short* __restrict__ Kh,   // [32][2048][64]
    const unsigned short* __restrict__ Vt,   // [32][64][2048]
    unsigned short* __restrict__ O)          // [4096][1024] bf16
{
    __shared__ char Ps[32 * 128];   // wave-private P (32 q-rows x 64 keys bf16, swizzled)

    const int lane = threadIdx.x;
    const int l15  = lane & 15;
    const int l4   = lane >> 4;
    const int g    = blockIdx.x;           // 0..2047
    const int qt   = 63 - (g >> 5);        // 32-row tile id, heavy first
    const int bh   = g & 31;
    const int b    = bh >> 4, h = bh & 15;
    const int q0w  = qt * 32;

    const unsigned short* hQ = Qh + (size_t)bh * GT_SEQ * GDH;
    const unsigned short* hK = Kh + (size_t)bh * GT_SEQ * GDH;
    const unsigned short* hV = Vt + (size_t)bh * GDH * GT_SEQ;

    // Q fragments (already scaled): qf[mi][s], d = s*32 + l4*8 + e
    bf16x8 qf[2][2];
#pragma unroll
    for (int mi = 0; mi < 2; ++mi)
#pragma unroll
        for (int s = 0; s < 2; ++s)
            qf[mi][s] = *reinterpret_cast<const bf16x8*>(
                hQ + (size_t)(q0w + mi * 16 + l15) * GDH + s * 32 + l4 * 8);

    f32x4 acc_o[2][4];
    float m_r[2][4], l_r[2][4];
#pragma unroll
    for (int mi = 0; mi < 2; ++mi)
#pragma unroll
        for (int j = 0; j < 4; ++j) { m_r[mi][j] = -1e30f; l_r[mi][j] = 0.f; }
#pragma unroll
    for (int mi = 0; mi < 2; ++mi)
#pragma unroll
        for (int nd = 0; nd < 4; ++nd) acc_o[mi][nd] = (f32x4){0.f, 0.f, 0.f, 0.f};

    const int ntiles = qt / 2 + 1;

    for (int kt = 0; kt < ntiles; ++kt) {
        const int k0 = kt * 64;

        // ---- QK^T: S[32 q][64 k], K fragments direct from global ----
        f32x4 s_acc[2][4];
#pragma unroll
        for (int mi = 0; mi < 2; ++mi)
#pragma unroll
            for (int ni = 0; ni < 4; ++ni) s_acc[mi][ni] = (f32x4){0.f, 0.f, 0.f, 0.f};
#pragma unroll
        for (int s = 0; s < 2; ++s) {
            bf16x8 kf[4];
#pragma unroll
            for (int ni = 0; ni < 4; ++ni)
                kf[ni] = *reinterpret_cast<const bf16x8*>(
                    hK + (size_t)(k0 + ni * 16 + l15) * GDH + s * 32 + l4 * 8);
#pragma unroll
            for (int mi = 0; mi < 2; ++mi)
#pragma unroll
                for (int ni = 0; ni < 4; ++ni)
                    s_acc[mi][ni] = __builtin_amdgcn_mfma_f32_16x16x32_bf16(
                        qf[mi][s], kf[ni], s_acc[mi][ni], 0, 0, 0);
        }

        // ---- to log2 domain + causal mask (only last tile is partial) ----
        const bool last = (kt == ntiles - 1);
#pragma unroll
        for (int mi = 0; mi < 2; ++mi)
#pragma unroll
            for (int ni = 0; ni < 4; ++ni)
#pragma unroll
                for (int j = 0; j < 4; ++j) {
                    float v = s_acc[mi][ni][j] * 1.44269504f;
                    if (last && (k0 + ni * 16 + l15 > q0w + mi * 16 + l4 * 4 + j))
                        v = -1e30f;
                    s_acc[mi][ni][j] = v;
                }

        // ---- row max + defer-max (T13, THR=8 in log2 domain) ----
        float rm[2][4];
        int small = 1;
#pragma unroll
        for (int mi = 0; mi < 2; ++mi)
#pragma unroll
            for (int j = 0; j < 4; ++j) {
                float r = fmaxf(fmaxf(s_acc[mi][0][j], s_acc[mi][1][j]),
                                fmaxf(s_acc[mi][2][j], s_acc[mi][3][j]));
                r = fmaxf(r, __shfl_xor(r, 1));
                r = fmaxf(r, __shfl_xor(r, 2));
                r = fmaxf(r, __shfl_xor(r, 4));
                r = fmaxf(r, __shfl_xor(r, 8));
                rm[mi][j] = r;
                small &= (r <= m_r[mi][j] + 8.f);
            }
        if (!__all(small)) {
#pragma unroll
            for (int mi = 0; mi < 2; ++mi)
#pragma unroll
                for (int j = 0; j < 4; ++j) {
                    const float mnew = fmaxf(m_r[mi][j], rm[mi][j]);
                    const float corr = hw_exp2(m_r[mi][j] - mnew);
                    m_r[mi][j] = mnew;
                    l_r[mi][j] *= corr;
#pragma unroll
                    for (int nd = 0; nd < 4; ++nd) acc_o[mi][nd][j] *= corr;
                }
        }

        // ---- P = exp2(s - m), write to wave-private LDS, row sums ----
#pragma unroll
        for (int mi = 0; mi < 2; ++mi)
#pragma unroll
            for (int j = 0; j < 4; ++j) {
                const int prow  = mi * 16 + l4 * 4 + j;
                const int pbase = prow * 128;
                const int psw   = prow & 7;
                float rs = 0.f;
#pragma unroll
                for (int ni = 0; ni < 4; ++ni) {
                    const float p = hw_exp2(s_acc[mi][ni][j] - m_r[mi][j]);
                    rs += p;
                    const int kcol = ni * 16 + l15;
                    *(unsigned short*)(Ps + pbase + (((kcol >> 3) ^ psw) << 4)
                                       + (kcol & 7) * 2) = f2bf(p);
                }
                rs += __shfl_xor(rs, 1);
                rs += __shfl_xor(rs, 2);
                rs += __shfl_xor(rs, 4);
                rs += __shfl_xor(rs, 8);
                l_r[mi][j] += rs;
            }

        // ---- PV: O += P @ V, V^T fragments direct from global ----
#pragma unroll
        for (int s = 0; s < 2; ++s) {
            bf16x8 pa[2], vb[4];
#pragma unroll
            for (int mi = 0; mi < 2; ++mi)
                pa[mi] = frag_ld(Ps, mi * 16 + l15, s * 4 + l4);
#pragma unroll
            for (int nd = 0; nd < 4; ++nd)
                vb[nd] = *reinterpret_cast<const bf16x8*>(
                    hV + (size_t)(nd * 16 + l15) * GT_SEQ + k0 + s * 32 + l4 * 8);
#pragma unroll
            for (int mi = 0; mi < 2; ++mi)
#pragma unroll
                for (int nd = 0; nd < 4; ++nd)
                    acc_o[mi][nd] = __builtin_amdgcn_mfma_f32_16x16x32_bf16(
                        pa[mi], vb[nd], acc_o[mi][nd], 0, 0, 0);
        }
    }

    // ---- epilogue: normalize, store bf16 [B,T,C] ----
#pragma unroll
    for (int mi = 0; mi < 2; ++mi)
#pragma unroll
        for (int j = 0; j < 4; ++j) {
            const float inv = 1.f / l_r[mi][j];
            const size_t rbase = (size_t)(b * GT_SEQ + q0w + mi * 16 + l4 * 4 + j) * GC
                               + h * GDH + l15;
#pragma unroll
            for (int nd = 0; nd < 4; ++nd)
                O[rbase + nd * 16] = f2bf(acc_o[mi][nd][j] * inv);
        }
}

extern "C" void kernel_launch(void* const* d_in, const int* in_sizes, int n_in,
                              void* d_out, int out_size, void* d_ws, size_t ws_size,
                              hipStream_t stream) {
    (void)in_sizes; (void)n_in; (void)out_size; (void)ws_size;
    const float* x      = (const float*)d_in[0];
    const float* w_attn = (const float*)d_in[1];
    const float* b_attn = (const float*)d_in[2];
    const float* w_proj = (const float*)d_in[3];
    const float* b_proj = (const float*)d_in[4];
    float* out = (float*)d_out;

    unsigned short* xb   = (unsigned short*)d_ws;            // [4096][1024]
    unsigned short* wab  = xb   + (size_t)GM * GC;           // [3072][1024]
    unsigned short* wpb  = wab  + (size_t)3 * GC * GC;       // [1024][1024]
    unsigned short* qkvb = wpb  + (size_t)GC * GC;           // [4096][3072]
    unsigned short* Qh   = qkvb + (size_t)GM * 3 * GC;       // [32][2048][64]
    unsigned short* Kh   = Qh   + (size_t)GM * GC;           // [32][2048][64]
    unsigned short* Vt   = Kh   + (size_t)GM * GC;           // [32][64][2048]
    unsigned short* aob  = xb;   // reuse: xb dead after GEMM1

    cast_f32_bf16<<<dim3(4096), dim3(256), 0, stream>>>(x,      xb,  GM * GC);
    cast_f32_bf16<<<dim3(3072), dim3(256), 0, stream>>>(w_attn, wab, 3 * GC * GC);
    cast_f32_bf16<<<dim3(1024), dim3(256), 0, stream>>>(w_proj, wpb, GC * GC);

    // 1) qkv = x @ w_attn^T + b_attn (bf16)
    gemm_mfma_bt<<<dim3(3 * GC / 128, GM / 128), dim3(256), 0, stream>>>(
        xb, wab, b_attn, nullptr, qkvb, GM, 3 * GC, GC);

    // 1.5) rearrange into per-head layouts (Q pre-scaled, V transposed)
    rearrange_qkv<<<dim3(GT_SEQ / 64, GB * GH), dim3(256), 0, stream>>>(
        qkvb, Qh, Kh, Vt);

    // 2) barrier-free flash attention -> aob [B,T,C] bf16
    flash_attn_mfma2<<<dim3(GB * GH * (GT_SEQ / 32)), dim3(64), 0, stream>>>(
        Qh, Kh, Vt, aob);

    // 3) out = aob @ w_proj^T + b_proj (f32)
    gemm_mfma_bt<<<dim3(GC / 128, GM / 128), dim3(256), 0, stream>>>(
        aob, wpb, b_proj, out, nullptr, GM, GC, GC);
}

// Round 6
// 157.728 us; speedup vs baseline: 6.1162x; 1.0655x over previous
//
#include <hip/hip_runtime.h>
#include <math.h>

// Problem constants: B=2, T=2048, C=1024, H=16, Dh=64
#define GB 2
#define GT_SEQ 2048
#define GC 1024
#define GH 16
#define GDH 64
#define GM (GB * GT_SEQ)      // 4096 rows

typedef __attribute__((ext_vector_type(8))) short bf16x8;   // 8 bf16 = 4 VGPRs
typedef __attribute__((ext_vector_type(8))) unsigned short u16x8;
typedef __attribute__((ext_vector_type(4))) float f32x4;

__device__ __forceinline__ unsigned short f2bf(float f) {   // RNE f32 -> bf16
    unsigned int u = __float_as_uint(f);
    u += 0x7FFFu + ((u >> 16) & 1u);
    return (unsigned short)(u >> 16);
}
__device__ __forceinline__ float bf2f(unsigned short u) {   // exact bf16 -> f32
    return __uint_as_float(((unsigned int)u) << 16);
}
// hardware 2^x (v_exp_f32)
__device__ __forceinline__ float hw_exp2(float x) {
    return __builtin_amdgcn_exp2f(x);
}

// async global->LDS, 16B per lane; LDS dest is wave-uniform base (+lane*16 by HW)
#define GLOAD_LDS16(g, l) __builtin_amdgcn_global_load_lds( \
    (const __attribute__((address_space(1))) void*)(g),      \
    (__attribute__((address_space(3))) void*)(l), 16, 0, 0)

// swizzled fragment read: rows of 64 bf16 (128B = 8 chunks), chunk ^= (row&7)
__device__ __forceinline__ bf16x8 frag_ld(const char* base, int r, int kch) {
    return *reinterpret_cast<const bf16x8*>(base + r * 128 + ((kch ^ (r & 7)) << 4));
}

// ---------------- cast f32 -> bf16 ----------------
__global__ __launch_bounds__(256) void cast_f32_bf16(
    const float* __restrict__ in, unsigned short* __restrict__ out, int n)
{
    const int i = (blockIdx.x * 256 + threadIdx.x) * 4;
    if (i + 3 < n) {
        const float4 v = *reinterpret_cast<const float4*>(&in[i]);
        ushort4 o;
        o.x = f2bf(v.x); o.y = f2bf(v.y); o.z = f2bf(v.z); o.w = f2bf(v.w);
        *reinterpret_cast<ushort4*>(&out[i]) = o;
    }
}

// ---------------- bf16 MFMA GEMM: C = A @ B^T + bias (validated rounds 2-5) ----------------
__global__ __launch_bounds__(256) void gemm_mfma_bt(
    const unsigned short* __restrict__ A,   // [M][K] bf16
    const unsigned short* __restrict__ B,   // [N][K] bf16
    const float* __restrict__ bias,         // [N] f32
    float* __restrict__ Cf,                 // f32 out (or null)
    unsigned short* __restrict__ Cb,        // bf16 out (or null)
    int M, int N, int K)
{
    __shared__ char As[128 * 128];
    __shared__ char Bs[128 * 128];

    const int tid  = threadIdx.x;
    const int lane = tid & 63;
    const int w    = tid >> 6;
    const int wm   = w >> 1;
    const int wn   = w & 1;
    const int m0 = blockIdx.y * 128;
    const int n0 = blockIdx.x * 128;

    f32x4 acc[4][4];
#pragma unroll
    for (int i = 0; i < 4; ++i)
#pragma unroll
        for (int j = 0; j < 4; ++j) acc[i][j] = (f32x4){0.f, 0.f, 0.f, 0.f};

    const int wbase = (tid & ~63);

    for (int k0 = 0; k0 < K; k0 += 64) {
        const char* Ag = (const char*)(A + (size_t)m0 * K + k0);
        const char* Bg = (const char*)(B + (size_t)n0 * K + k0);
#pragma unroll
        for (int i = 0; i < 4; ++i) {
            const int c = i * 256 + tid;
            const int row = c >> 3, cin = c & 7;
            const size_t goff = (size_t)row * (K * 2) + (size_t)((cin ^ (row & 7)) << 4);
            GLOAD_LDS16(Ag + goff, As + (i * 256 + wbase) * 16);
            GLOAD_LDS16(Bg + goff, Bs + (i * 256 + wbase) * 16);
        }
        __syncthreads();

#pragma unroll
        for (int ks = 0; ks < 2; ++ks) {
            const int kch = ks * 4 + (lane >> 4);
            bf16x8 a[4], b[4];
#pragma unroll
            for (int mi = 0; mi < 4; ++mi)
                a[mi] = frag_ld(As, wm * 64 + mi * 16 + (lane & 15), kch);
#pragma unroll
            for (int ni = 0; ni < 4; ++ni)
                b[ni] = frag_ld(Bs, wn * 64 + ni * 16 + (lane & 15), kch);
#pragma unroll
            for (int mi = 0; mi < 4; ++mi)
#pragma unroll
                for (int ni = 0; ni < 4; ++ni)
                    acc[mi][ni] = __builtin_amdgcn_mfma_f32_16x16x32_bf16(
                        a[mi], b[ni], acc[mi][ni], 0, 0, 0);
        }
        __syncthreads();
    }

    const int lc  = lane & 15;
    const int lr4 = (lane >> 4) * 4;
#pragma unroll
    for (int ni = 0; ni < 4; ++ni) {
        const int gcol = n0 + wn * 64 + ni * 16 + lc;
        const float bv = bias[gcol];
#pragma unroll
        for (int mi = 0; mi < 4; ++mi) {
            const int grow0 = m0 + wm * 64 + mi * 16 + lr4;
#pragma unroll
            for (int j = 0; j < 4; ++j) {
                const float v = acc[mi][ni][j] + bv;
                if (Cb) Cb[(size_t)(grow0 + j) * N + gcol] = f2bf(v);
                else    Cf[(size_t)(grow0 + j) * N + gcol] = v;
            }
        }
    }
}

// ---------------- rearrange qkv -> per-head Q (pre-scaled to log2 domain), K, V^T ----------------
// Qh/Kh: [bh][t][d];  Vt: [bh][d][t].  Q scale = 0.125 * log2(e).
__global__ __launch_bounds__(256) void rearrange_qkv(
    const unsigned short* __restrict__ qkv,  // [4096][3072]
    unsigned short* __restrict__ Qh,
    unsigned short* __restrict__ Kh,
    unsigned short* __restrict__ Vt)
{
    __shared__ unsigned short vtile[64][72];   // [t][d], padded

    const int tid = threadIdx.x;
    const int tt  = blockIdx.x;     // t-tile 0..31
    const int bh  = blockIdx.y;     // 0..31
    const int b = bh >> 4, h = bh & 15;
    const int t0 = tt * 64;

    const size_t srow = (size_t)(b * GT_SEQ + t0) * (3 * GC) + h * GDH;
    const size_t drow = (size_t)bh * GT_SEQ * GDH + (size_t)t0 * GDH;

#pragma unroll
    for (int i = 0; i < 2; ++i) {
        const int c  = i * 256 + tid;      // 0..511
        const int tr = c >> 3, ch = c & 7; // row in tile, 16B chunk
        const size_t s = srow + (size_t)tr * (3 * GC) + ch * 8;
        // Q: scale by 0.125 * log2(e) -> QK^T lands directly in log2 domain
        u16x8 q = *reinterpret_cast<const u16x8*>(qkv + s);
        u16x8 qo;
#pragma unroll
        for (int e = 0; e < 8; ++e) qo[e] = f2bf(bf2f(q[e]) * 0.18033688f);
        *reinterpret_cast<u16x8*>(Qh + drow + tr * GDH + ch * 8) = qo;
        // K: straight copy
        *reinterpret_cast<u16x8*>(Kh + drow + tr * GDH + ch * 8) =
            *reinterpret_cast<const u16x8*>(qkv + s + GC);
        // V -> LDS tile
        *reinterpret_cast<u16x8*>(&vtile[tr][ch * 8]) =
            *reinterpret_cast<const u16x8*>(qkv + s + 2 * GC);
    }
    __syncthreads();

    // transposed writeout: Vt[bh][d][t0..t0+63]
#pragma unroll
    for (int i = 0; i < 2; ++i) {
        const int c  = i * 256 + tid;
        const int d  = c >> 3, ch = c & 7;   // d row, 8-t chunk
        u16x8 o;
#pragma unroll
        for (int e = 0; e < 8; ++e) o[e] = vtile[ch * 8 + e][d];
        *reinterpret_cast<u16x8*>(
            Vt + (size_t)bh * GDH * GT_SEQ + (size_t)d * GT_SEQ + t0 + ch * 8) = o;
    }
}

// ---------------- barrier-free MFMA flash attention v3 ----------------
// One wave per 32-row Q tile. K prefetched one tile ahead (registers), V issued
// early in-body. Row sums via MFMA ones-column; row max via deferred-max fast
// path (no shuffles steady-state). Only LDS: wave-private 4KB P round-trip.
__global__ __launch_bounds__(64, 2) void flash_attn_mfma3(
    const unsigned short* __restrict__ Qh,   // [32][2048][64], pre-scaled
    const unsigned short* __restrict__ Kh,   // [32][2048][64]
    const unsigned short* __restrict__ Vt,   // [32][64][2048]
    unsigned short* __restrict__ O)          // [4096][1024] bf16
{
    __shared__ char Ps[32 * 128];   // 32 q-rows x 64 keys bf16, swizzled

    const int lane = threadIdx.x;
    const int l15  = lane & 15;
    const int l4   = lane >> 4;
    const int bid  = blockIdx.x;             // 0..2047
    // XCD swizzle: xcd (bid&7) serves heads 4*xcd..4*xcd+3; heavy q-tiles first
    const int bh   = (bid & 7) * 4 + ((bid >> 3) & 3);
    const int qt   = 63 - (bid >> 5);
    const int b    = bh >> 4, h = bh & 15;
    const int q0w  = qt * 32;

    const unsigned short* hQ = Qh + (size_t)bh * GT_SEQ * GDH;
    const unsigned short* hK = Kh + (size_t)bh * GT_SEQ * GDH;
    const unsigned short* hV = Vt + (size_t)bh * GDH * GT_SEQ;

    // ones B-fragment: synthetic V^T row n=64 (all ones) -> D col 64 = row sum
    bf16x8 ones_b;
    {
        const short ov = (l15 == 0) ? (short)0x3F80 : (short)0;
#pragma unroll
        for (int e = 0; e < 8; ++e) ones_b[e] = ov;
    }

    // Q fragments (pre-scaled): qf[mi][s], d = s*32 + l4*8 + e
    bf16x8 qf[2][2];
#pragma unroll
    for (int mi = 0; mi < 2; ++mi)
#pragma unroll
        for (int s = 0; s < 2; ++s)
            qf[mi][s] = *reinterpret_cast<const bf16x8*>(
                hQ + (size_t)(q0w + mi * 16 + l15) * GDH + s * 32 + l4 * 8);

    f32x4 acc_o[2][4];
    f32x4 acc_l[2];
    float m_r[2][4];
#pragma unroll
    for (int mi = 0; mi < 2; ++mi) {
        acc_l[mi] = (f32x4){0.f, 0.f, 0.f, 0.f};
#pragma unroll
        for (int j = 0; j < 4; ++j) m_r[mi][j] = -1e30f;
#pragma unroll
        for (int nd = 0; nd < 4; ++nd) acc_o[mi][nd] = (f32x4){0.f, 0.f, 0.f, 0.f};
    }

    const int nt = qt / 2 + 1;

    // prologue: K fragments for tile 0
    bf16x8 kfc[8];
#pragma unroll
    for (int s = 0; s < 2; ++s)
#pragma unroll
        for (int ni = 0; ni < 4; ++ni)
            kfc[s * 4 + ni] = *reinterpret_cast<const bf16x8*>(
                hK + (size_t)(ni * 16 + l15) * GDH + s * 32 + l4 * 8);

    for (int kt = 0; kt < nt; ++kt) {
        const int k0  = kt * 64;
        const int kn0 = (kt + 1 < nt ? kt + 1 : kt) * 64;

        // issue V loads for this tile early (consumed after softmax)
        bf16x8 vb[8];
#pragma unroll
        for (int s = 0; s < 2; ++s)
#pragma unroll
            for (int nd = 0; nd < 4; ++nd)
                vb[s * 4 + nd] = *reinterpret_cast<const bf16x8*>(
                    hV + (size_t)(nd * 16 + l15) * GT_SEQ + k0 + s * 32 + l4 * 8);

        // issue next-tile K loads (consumed next iteration)
        bf16x8 kfn[8];
#pragma unroll
        for (int s = 0; s < 2; ++s)
#pragma unroll
            for (int ni = 0; ni < 4; ++ni)
                kfn[s * 4 + ni] = *reinterpret_cast<const bf16x8*>(
                    hK + (size_t)(kn0 + ni * 16 + l15) * GDH + s * 32 + l4 * 8);

        // ---- QK^T: S[32 q][64 k] in log2 domain (Q pre-scaled) ----
        f32x4 s_acc[2][4];
#pragma unroll
        for (int mi = 0; mi < 2; ++mi)
#pragma unroll
            for (int ni = 0; ni < 4; ++ni) s_acc[mi][ni] = (f32x4){0.f, 0.f, 0.f, 0.f};
#pragma unroll
        for (int s = 0; s < 2; ++s)
#pragma unroll
            for (int mi = 0; mi < 2; ++mi)
#pragma unroll
                for (int ni = 0; ni < 4; ++ni)
                    s_acc[mi][ni] = __builtin_amdgcn_mfma_f32_16x16x32_bf16(
                        qf[mi][s], kfc[s * 4 + ni], s_acc[mi][ni], 0, 0, 0);

        // ---- causal mask (only last tile is partial) ----
        if (kt == nt - 1) {
#pragma unroll
            for (int mi = 0; mi < 2; ++mi)
#pragma unroll
                for (int ni = 0; ni < 4; ++ni)
#pragma unroll
                    for (int j = 0; j < 4; ++j)
                        if (k0 + ni * 16 + l15 > q0w + mi * 16 + l4 * 4 + j)
                            s_acc[mi][ni][j] = -1e30f;
        }

        // ---- deferred-max: in-lane partial max + wave-wide check ----
        float rp[2][4];
        int ok = 1;
#pragma unroll
        for (int mi = 0; mi < 2; ++mi)
#pragma unroll
            for (int j = 0; j < 4; ++j) {
                const float r = fmaxf(fmaxf(s_acc[mi][0][j], s_acc[mi][1][j]),
                                      fmaxf(s_acc[mi][2][j], s_acc[mi][3][j]));
                rp[mi][j] = r;
                ok &= (r <= m_r[mi][j] + 8.f) ? 1 : 0;
            }
        if (!__all(ok)) {   // slow path: full row max + rescale (rare)
#pragma unroll
            for (int mi = 0; mi < 2; ++mi)
#pragma unroll
                for (int j = 0; j < 4; ++j) {
                    float r = rp[mi][j];
                    r = fmaxf(r, __shfl_xor(r, 1));
                    r = fmaxf(r, __shfl_xor(r, 2));
                    r = fmaxf(r, __shfl_xor(r, 4));
                    r = fmaxf(r, __shfl_xor(r, 8));
                    const float mnew = fmaxf(m_r[mi][j], r);
                    const float corr = hw_exp2(m_r[mi][j] - mnew);
                    m_r[mi][j] = mnew;
                    acc_l[mi][j] *= corr;
#pragma unroll
                    for (int nd = 0; nd < 4; ++nd) acc_o[mi][nd][j] *= corr;
                }
        }

        // ---- P = exp2(s - m) -> wave-private LDS (bf16, swizzled) ----
#pragma unroll
        for (int mi = 0; mi < 2; ++mi)
#pragma unroll
            for (int j = 0; j < 4; ++j) {
                const int prow  = mi * 16 + l4 * 4 + j;
                const int pbase = prow * 128;
                const int psw   = prow & 7;
#pragma unroll
                for (int ni = 0; ni < 4; ++ni) {
                    const float p = hw_exp2(s_acc[mi][ni][j] - m_r[mi][j]);
                    const int kcol = ni * 16 + l15;
                    *(unsigned short*)(Ps + pbase + (((kcol >> 3) ^ psw) << 4)
                                       + (kcol & 7) * 2) = f2bf(p);
                }
            }

        // ---- PV + row-sum column: O += P@V, l += P@ones ----
#pragma unroll
        for (int s = 0; s < 2; ++s) {
            bf16x8 pa[2];
            pa[0] = frag_ld(Ps, l15,      s * 4 + l4);
            pa[1] = frag_ld(Ps, 16 + l15, s * 4 + l4);
#pragma unroll
            for (int mi = 0; mi < 2; ++mi) {
                acc_l[mi] = __builtin_amdgcn_mfma_f32_16x16x32_bf16(
                    pa[mi], ones_b, acc_l[mi], 0, 0, 0);
#pragma unroll
                for (int nd = 0; nd < 4; ++nd)
                    acc_o[mi][nd] = __builtin_amdgcn_mfma_f32_16x16x32_bf16(
                        pa[mi], vb[s * 4 + nd], acc_o[mi][nd], 0, 0, 0);
            }
        }

        // rotate K prefetch (static copies)
#pragma unroll
        for (int i = 0; i < 8; ++i) kfc[i] = kfn[i];
    }

    // ---- epilogue: broadcast row sum from l15==0 lane, normalize, store ----
#pragma unroll
    for (int mi = 0; mi < 2; ++mi)
#pragma unroll
        for (int j = 0; j < 4; ++j) {
            const float lsum = __shfl(acc_l[mi][j], lane & 48);
            const float inv = 1.f / lsum;
            const size_t rbase = (size_t)(b * GT_SEQ + q0w + mi * 16 + l4 * 4 + j) * GC
                               + h * GDH + l15;
#pragma unroll
            for (int nd = 0; nd < 4; ++nd)
                O[rbase + nd * 16] = f2bf(acc_o[mi][nd][j] * inv);
        }
}

extern "C" void kernel_launch(void* const* d_in, const int* in_sizes, int n_in,
                              void* d_out, int out_size, void* d_ws, size_t ws_size,
                              hipStream_t stream) {
    (void)in_sizes; (void)n_in; (void)out_size; (void)ws_size;
    const float* x      = (const float*)d_in[0];
    const float* w_attn = (const float*)d_in[1];
    const float* b_attn = (const float*)d_in[2];
    const float* w_proj = (const float*)d_in[3];
    const float* b_proj = (const float*)d_in[4];
    float* out = (float*)d_out;

    unsigned short* xb   = (unsigned short*)d_ws;            // [4096][1024]
    unsigned short* wab  = xb   + (size_t)GM * GC;           // [3072][1024]
    unsigned short* wpb  = wab  + (size_t)3 * GC * GC;       // [1024][1024]
    unsigned short* qkvb = wpb  + (size_t)GC * GC;           // [4096][3072]
    unsigned short* Qh   = qkvb + (size_t)GM * 3 * GC;       // [32][2048][64]
    unsigned short* Kh   = Qh   + (size_t)GM * GC;           // [32][2048][64]
    unsigned short* Vt   = Kh   + (size_t)GM * GC;           // [32][64][2048]
    unsigned short* aob  = xb;   // reuse: xb dead after GEMM1

    cast_f32_bf16<<<dim3(4096), dim3(256), 0, stream>>>(x,      xb,  GM * GC);
    cast_f32_bf16<<<dim3(3072), dim3(256), 0, stream>>>(w_attn, wab, 3 * GC * GC);
    cast_f32_bf16<<<dim3(1024), dim3(256), 0, stream>>>(w_proj, wpb, GC * GC);

    // 1) qkv = x @ w_attn^T + b_attn (bf16)
    gemm_mfma_bt<<<dim3(3 * GC / 128, GM / 128), dim3(256), 0, stream>>>(
        xb, wab, b_attn, nullptr, qkvb, GM, 3 * GC, GC);

    // 1.5) rearrange into per-head layouts (Q pre-scaled to log2 domain, V transposed)
    rearrange_qkv<<<dim3(GT_SEQ / 64, GB * GH), dim3(256), 0, stream>>>(
        qkvb, Qh, Kh, Vt);

    // 2) barrier-free flash attention v3 -> aob [B,T,C] bf16
    flash_attn_mfma3<<<dim3(GB * GH * (GT_SEQ / 32)), dim3(64), 0, stream>>>(
        Qh, Kh, Vt, aob);

    // 3) out = aob @ w_proj^T + b_proj (f32)
    gemm_mfma_bt<<<dim3(GC / 128, GM / 128), dim3(256), 0, stream>>>(
        aob, wpb, b_proj, out, nullptr, GM, GC, GC);
}